// Round 1
// baseline (1007.155 us; speedup 1.0000x reference)
//
#include <hip/hip_runtime.h>
#include <cstddef>

// Problem constants (B,S,H,D fixed by the reference)
constexpr int Bc = 2, Sc = 2048, Hc = 16, Dc = 64, HIDc = 1024;
#define NEG_INF -10000.0f

// ---------------------------------------------------------------------------
// Kernel 1: fused QKV projection.  C[m,n] = x[m,:] @ W[:,n] + bias[n]
// M = B*S = 4096, N = HID = 1024, K = HID = 1024.  z selects {Q,K,V}.
// Output layout: [b, h, s, d]  (natural for the attention kernel).
// Tile: BM=64, BN=64, BK=16, 256 threads, 4x4 micro-tile per thread.
// ---------------------------------------------------------------------------
__global__ __launch_bounds__(256) void qkv_proj_kernel(
    const float* __restrict__ x,
    const float* __restrict__ Wq, const float* __restrict__ bq,
    const float* __restrict__ Wk, const float* __restrict__ bk,
    const float* __restrict__ Wv, const float* __restrict__ bv,
    float* __restrict__ qw, float* __restrict__ kw, float* __restrict__ vw)
{
    const int z = blockIdx.z;
    const float* __restrict__ W    = (z == 0) ? Wq : (z == 1) ? Wk : Wv;
    const float* __restrict__ bias = (z == 0) ? bq : (z == 1) ? bk : bv;
    float* __restrict__ out        = (z == 0) ? qw : (z == 1) ? kw : vw;

    // As: x-tile transposed [k][m], stride 65 so transpose writes are ~2-way.
    __shared__ float As[16][65];
    // Bs: W-tile natural [k][n], stride 64 (float4-aligned, 2-way reads).
    __shared__ float Bs[16][64];

    const int t  = threadIdx.x;
    const int tx = t & 15, ty = t >> 4;
    const int m0 = blockIdx.y * 64;
    const int n0 = blockIdx.x * 64;

    // staging index decomposition
    const int mr = t >> 2;          // 0..63   row of x tile
    const int kc = (t & 3) << 2;    // 0,4,8,12 k-offset (float4)
    const int kr = t >> 4;          // 0..15   row of W tile
    const int nc = (t & 15) << 2;   // 0..60   n-offset (float4)

    float acc[4][4] = {};

    for (int k0 = 0; k0 < HIDc; k0 += 16) {
        // issue global loads before the barrier so they overlap prior compute
        float4 xa = *(const float4*)(x + (m0 + mr) * HIDc + k0 + kc);
        float4 wa = *(const float4*)(W + (k0 + kr) * HIDc + n0 + nc);
        __syncthreads();                         // prior readers done
        As[kc + 0][mr] = xa.x;
        As[kc + 1][mr] = xa.y;
        As[kc + 2][mr] = xa.z;
        As[kc + 3][mr] = xa.w;
        *(float4*)&Bs[kr][nc] = wa;
        __syncthreads();

        #pragma unroll
        for (int kk = 0; kk < 16; ++kk) {
            float a[4], bb[4];
            #pragma unroll
            for (int i = 0; i < 4; ++i) a[i] = As[kk][4 * ty + i];
            float4 b4 = *(float4*)&Bs[kk][4 * tx];
            bb[0] = b4.x; bb[1] = b4.y; bb[2] = b4.z; bb[3] = b4.w;
            #pragma unroll
            for (int i = 0; i < 4; ++i)
                #pragma unroll
                for (int j = 0; j < 4; ++j)
                    acc[i][j] = fmaf(a[i], bb[j], acc[i][j]);
        }
    }

    const float4 bv4 = *(const float4*)(bias + n0 + 4 * tx);
    const int h = n0 >> 6;  // BN=64 == head dim, so one head per tile
    #pragma unroll
    for (int i = 0; i < 4; ++i) {
        int m  = m0 + 4 * ty + i;
        int bI = m >> 11;           // m / S
        int s  = m & (Sc - 1);
        float4 r;
        r.x = acc[i][0] + bv4.x;
        r.y = acc[i][1] + bv4.y;
        r.z = acc[i][2] + bv4.z;
        r.w = acc[i][3] + bv4.w;
        *(float4*)(out + ((size_t)((bI * Hc + h) * Sc + s)) * Dc + 4 * tx) = r;
    }
}

// ---------------------------------------------------------------------------
// Kernel 2: flash attention.  One block = one (b,h) x 64-query tile.
// Q,K staged transposed [d][row] (stride 65: transpose writes & reads 2-way,
// i.e. free).  V natural [row][d].  P aliases the K buffer (written after all
// K reads complete).  Online softmax; row stats reduced over the 16 lanes
// that share a query row via __shfl_xor (groups are 16-aligned in the wave).
// ---------------------------------------------------------------------------
__global__ __launch_bounds__(256) void attn_kernel(
    const float* __restrict__ qw, const float* __restrict__ kw,
    const float* __restrict__ vw, const int* __restrict__ mask,
    float* __restrict__ out)
{
    __shared__ float Qs[64][65];   // [d][q], pre-scaled by 1/sqrt(D)
    __shared__ float KP[64][65];   // [d][key] as K, then [key][q] as P
    __shared__ float Vs[64][64];   // [key][d]

    const int t  = threadIdx.x;
    const int tx = t & 15, ty = t >> 4;
    const int q0 = blockIdx.x * 64;
    const int bh = blockIdx.y;          // b*H + h
    const int bI = bh >> 4, h = bh & 15;

    const float* __restrict__ Qp = qw + (size_t)bh * Sc * Dc;
    const float* __restrict__ Kp = kw + (size_t)bh * Sc * Dc;
    const float* __restrict__ Vp = vw + (size_t)bh * Sc * Dc;
    const int*   __restrict__ mp = mask + bI * Sc;

    // ---- load Q tile once, transposed + scaled -------------------------
    #pragma unroll
    for (int l = 0; l < 4; ++l) {
        int idx = t + 256 * l;
        int row = idx >> 4;             // 0..63
        int c4  = (idx & 15) << 2;      // 0..60
        float4 v = *(const float4*)(Qp + (q0 + row) * Dc + c4);
        Qs[c4 + 0][row] = v.x * 0.125f;
        Qs[c4 + 1][row] = v.y * 0.125f;
        Qs[c4 + 2][row] = v.z * 0.125f;
        Qs[c4 + 3][row] = v.w * 0.125f;
    }

    float o[4][4] = {};
    float mrow[4] = {-1e30f, -1e30f, -1e30f, -1e30f};
    float lrow[4] = {};

    for (int kt = 0; kt < Sc; kt += 64) {
        // additive mask for this thread's 4 key columns
        float ad[4];
        #pragma unroll
        for (int j = 0; j < 4; ++j)
            ad[j] = (1.0f - (float)mp[kt + 4 * tx + j]) * NEG_INF;

        __syncthreads();   // previous tile's PV readers done with KP/Vs
        #pragma unroll
        for (int l = 0; l < 4; ++l) {
            int idx = t + 256 * l;
            int row = idx >> 4;
            int c4  = (idx & 15) << 2;
            float4 kv4 = *(const float4*)(Kp + (kt + row) * Dc + c4);
            KP[c4 + 0][row] = kv4.x;
            KP[c4 + 1][row] = kv4.y;
            KP[c4 + 2][row] = kv4.z;
            KP[c4 + 3][row] = kv4.w;
            float4 vv4 = *(const float4*)(Vp + (kt + row) * Dc + c4);
            *(float4*)&Vs[row][c4] = vv4;
        }
        __syncthreads();

        // ---- S = (Q/8) @ K^T  -----------------------------------------
        float sc[4][4] = {};
        #pragma unroll 8
        for (int kk = 0; kk < 64; ++kk) {
            float a[4], bb[4];
            #pragma unroll
            for (int i = 0; i < 4; ++i) a[i]  = Qs[kk][4 * ty + i];
            #pragma unroll
            for (int j = 0; j < 4; ++j) bb[j] = KP[kk][4 * tx + j];
            #pragma unroll
            for (int i = 0; i < 4; ++i)
                #pragma unroll
                for (int j = 0; j < 4; ++j)
                    sc[i][j] = fmaf(a[i], bb[j], sc[i][j]);
        }
        #pragma unroll
        for (int i = 0; i < 4; ++i)
            #pragma unroll
            for (int j = 0; j < 4; ++j)
                sc[i][j] += ad[j];

        // ---- online softmax -------------------------------------------
        float pm[4];
        #pragma unroll
        for (int i = 0; i < 4; ++i)
            pm[i] = fmaxf(fmaxf(sc[i][0], sc[i][1]), fmaxf(sc[i][2], sc[i][3]));
        #pragma unroll
        for (int off = 1; off < 16; off <<= 1)
            #pragma unroll
            for (int i = 0; i < 4; ++i)
                pm[i] = fmaxf(pm[i], __shfl_xor(pm[i], off, 64));

        float rs[4];
        #pragma unroll
        for (int i = 0; i < 4; ++i) {
            float mn = fmaxf(mrow[i], pm[i]);
            float al = __expf(mrow[i] - mn);
            mrow[i] = mn;
            float s0 = 0.f;
            #pragma unroll
            for (int j = 0; j < 4; ++j) {
                float p = __expf(sc[i][j] - mn);
                sc[i][j] = p;
                s0 += p;
            }
            rs[i] = s0;
            lrow[i] *= al;
            #pragma unroll
            for (int j = 0; j < 4; ++j) o[i][j] *= al;
        }
        #pragma unroll
        for (int off = 1; off < 16; off <<= 1)
            #pragma unroll
            for (int i = 0; i < 4; ++i)
                rs[i] += __shfl_xor(rs[i], off, 64);
        #pragma unroll
        for (int i = 0; i < 4; ++i) lrow[i] += rs[i];

        // ---- P into LDS (reuse KP as [key][q]) ------------------------
        __syncthreads();   // all threads done reading KP as K
        #pragma unroll
        for (int i = 0; i < 4; ++i)
            #pragma unroll
            for (int j = 0; j < 4; ++j)
                KP[4 * tx + j][4 * ty + i] = sc[i][j];
        __syncthreads();

        // ---- O += P @ V ----------------------------------------------
        #pragma unroll 8
        for (int kk = 0; kk < 64; ++kk) {
            float a[4], bb[4];
            #pragma unroll
            for (int i = 0; i < 4; ++i) a[i] = KP[kk][4 * ty + i];
            float4 b4 = *(float4*)&Vs[kk][4 * tx];
            bb[0] = b4.x; bb[1] = b4.y; bb[2] = b4.z; bb[3] = b4.w;
            #pragma unroll
            for (int i = 0; i < 4; ++i)
                #pragma unroll
                for (int j = 0; j < 4; ++j)
                    o[i][j] = fmaf(a[i], bb[j], o[i][j]);
        }
    }

    // ---- epilogue: normalize, write [b, s, h*D + d] -------------------
    #pragma unroll
    for (int i = 0; i < 4; ++i) {
        float inv = 1.0f / lrow[i];
        int q = q0 + 4 * ty + i;
        float4 r;
        r.x = o[i][0] * inv;
        r.y = o[i][1] * inv;
        r.z = o[i][2] * inv;
        r.w = o[i][3] * inv;
        *(float4*)(out + ((size_t)(bI * Sc + q)) * HIDc + h * Dc + 4 * tx) = r;
    }
}

// ---------------------------------------------------------------------------
extern "C" void kernel_launch(void* const* d_in, const int* in_sizes, int n_in,
                              void* d_out, int out_size, void* d_ws, size_t ws_size,
                              hipStream_t stream) {
    const float* x    = (const float*)d_in[0];
    const int*   mask = (const int*)  d_in[1];
    const float* Wq   = (const float*)d_in[2];
    const float* bq   = (const float*)d_in[3];
    const float* Wk   = (const float*)d_in[4];
    const float* bk   = (const float*)d_in[5];
    const float* Wv   = (const float*)d_in[6];
    const float* bv   = (const float*)d_in[7];
    float* out = (float*)d_out;

    // workspace: Q, K, V each B*H*S*D floats (16 MB) -> 48 MB total
    const size_t per = (size_t)Bc * Hc * Sc * Dc;
    float* qw = (float*)d_ws;
    float* kw = qw + per;
    float* vw = kw + per;

    qkv_proj_kernel<<<dim3(HIDc / 64, (Bc * Sc) / 64, 3), 256, 0, stream>>>(
        x, Wq, bq, Wk, bk, Wv, bv, qw, kw, vw);
    attn_kernel<<<dim3(Sc / 64, Bc * Hc), 256, 0, stream>>>(
        qw, kw, vw, mask, out);
}

// Round 4
// 721.833 us; speedup vs baseline: 1.3953x; 1.3953x over previous
//
#include <hip/hip_runtime.h>
#include <cstddef>

constexpr int Bc = 2, Sc = 2048, Hc = 16, Dc = 64, HIDc = 1024;
#define NEG_INF -10000.0f

typedef _Float16 half8  __attribute__((ext_vector_type(8)));  // MFMA A/B frag (4 VGPRs)
typedef float   floatx4 __attribute__((ext_vector_type(4)));  // MFMA C/D frag

// ---------------------------------------------------------------------------
// proj (fp32 VALU — the Round-1 end-to-end-verified kernel; only the stores
// changed: f16 output, Q pre-scaled by 1/8, V stored transposed [b,h,d,s]).
// C[m,n] = x[m,:] @ W[:,n] + bias[n];  M=4096, N=K=1024; z selects {Q,K,V}.
// Tile: BM=64, BN=64, BK=16, 256 threads, 4x4 micro-tile per thread.
// ---------------------------------------------------------------------------
__global__ __launch_bounds__(256) void qkv_proj_kernel(
    const float* __restrict__ x,
    const float* __restrict__ Wq, const float* __restrict__ bq,
    const float* __restrict__ Wk, const float* __restrict__ bk,
    const float* __restrict__ Wv, const float* __restrict__ bv,
    _Float16* __restrict__ qw, _Float16* __restrict__ kw, _Float16* __restrict__ vt)
{
    const int z = blockIdx.z;
    const float* __restrict__ W    = (z == 0) ? Wq : (z == 1) ? Wk : Wv;
    const float* __restrict__ bias = (z == 0) ? bq : (z == 1) ? bk : bv;

    __shared__ float As[16][65];   // x-tile transposed [k][m]
    __shared__ float Bs[16][64];   // W-tile natural [k][n]

    const int t  = threadIdx.x;
    const int tx = t & 15, ty = t >> 4;
    const int m0 = blockIdx.y * 64;
    const int n0 = blockIdx.x * 64;

    const int mr = t >> 2;          // 0..63 x-row
    const int kc = (t & 3) << 2;    // k offset (float4)
    const int kr = t >> 4;          // 0..15 W-row
    const int nc = (t & 15) << 2;   // n offset (float4)

    float acc[4][4] = {};

    for (int k0 = 0; k0 < HIDc; k0 += 16) {
        float4 xa = *(const float4*)(x + (m0 + mr) * HIDc + k0 + kc);
        float4 wa = *(const float4*)(W + (k0 + kr) * HIDc + n0 + nc);
        __syncthreads();
        As[kc + 0][mr] = xa.x;
        As[kc + 1][mr] = xa.y;
        As[kc + 2][mr] = xa.z;
        As[kc + 3][mr] = xa.w;
        *(float4*)&Bs[kr][nc] = wa;
        __syncthreads();

        #pragma unroll
        for (int kk = 0; kk < 16; ++kk) {
            float a[4], bb[4];
            #pragma unroll
            for (int i = 0; i < 4; ++i) a[i] = As[kk][4 * ty + i];
            float4 b4 = *(float4*)&Bs[kk][4 * tx];
            bb[0] = b4.x; bb[1] = b4.y; bb[2] = b4.z; bb[3] = b4.w;
            #pragma unroll
            for (int i = 0; i < 4; ++i)
                #pragma unroll
                for (int j = 0; j < 4; ++j)
                    acc[i][j] = fmaf(a[i], bb[j], acc[i][j]);
        }
    }

    const float4 bv4 = *(const float4*)(bias + n0 + 4 * tx);
    const float bia[4] = {bv4.x, bv4.y, bv4.z, bv4.w};
    const int h = n0 >> 6;          // BN=64 == head dim
    #pragma unroll
    for (int i = 0; i < 4; ++i) {
        const int m  = m0 + 4 * ty + i;
        const int bI = m >> 11;
        const int s  = m & (Sc - 1);
        #pragma unroll
        for (int j = 0; j < 4; ++j) {
            const int d = 4 * tx + j;
            const float v = acc[i][j] + bia[j];
            if (z == 0)
                qw[(((size_t)(bI * Hc + h)) * Sc + s) * Dc + d] = (_Float16)(v * 0.125f);
            else if (z == 1)
                kw[(((size_t)(bI * Hc + h)) * Sc + s) * Dc + d] = (_Float16)v;
            else
                vt[(((size_t)(bI * Hc + h)) * Dc + d) * Sc + s] = (_Float16)v;
        }
    }
}

// ---------------------------------------------------------------------------
// attn: flash attention, f16 MFMA — UNCHANGED from Round 3 (isolation round:
// proj above is the R1-verified fp32 kernel, so a pass exonerates this kernel
// and a ~500-scale fail indicts it).
// ---------------------------------------------------------------------------
__global__ __launch_bounds__(256) void attn_kernel(
    const _Float16* __restrict__ qw, const _Float16* __restrict__ kw,
    const _Float16* __restrict__ vt, const int* __restrict__ mask,
    float* __restrict__ out)
{
    __shared__ float adder[Sc];              // 8 KB additive mask
    __shared__ _Float16 Pw[4][16 * 72];      // 9 KB, per-wave P strips

    const int t = threadIdx.x;
    const int lane = t & 63, w = t >> 6;
    const int quad = lane >> 4, l16 = lane & 15;
    const int qt = blockIdx.x, bh = blockIdx.y;
    const int bI = bh >> 4, h = bh & 15;

    const _Float16* Qp = qw + (size_t)bh * Sc * Dc;
    const _Float16* Kp = kw + (size_t)bh * Sc * Dc;
    const _Float16* Vp = vt + (size_t)bh * Dc * Sc;

    {   // mask -> additive adder in LDS
        const int4* mp = (const int4*)(mask + bI * Sc);
        #pragma unroll
        for (int i = 0; i < 2; ++i) {
            int4 m4 = mp[t * 2 + i];
            int base = (t * 2 + i) * 4;
            adder[base + 0] = (1.0f - (float)m4.x) * NEG_INF;
            adder[base + 1] = (1.0f - (float)m4.y) * NEG_INF;
            adder[base + 2] = (1.0f - (float)m4.z) * NEG_INF;
            adder[base + 3] = (1.0f - (float)m4.w) * NEG_INF;
        }
    }
    __syncthreads();

    const int qrow = qt * 64 + w * 16;
    // Q A-frags (pre-scaled 1/8 in proj): A[m=l16][k=quad*8+j]
    const half8 aq0 = *(const half8*)(Qp + (size_t)(qrow + l16) * Dc + quad * 8);
    const half8 aq1 = *(const half8*)(Qp + (size_t)(qrow + l16) * Dc + 32 + quad * 8);

    floatx4 o[4];
    #pragma unroll
    for (int nb = 0; nb < 4; ++nb) o[nb] = floatx4{0.f, 0.f, 0.f, 0.f};
    float mrun[4] = {-1e30f, -1e30f, -1e30f, -1e30f};
    float lrun[4] = {0.f, 0.f, 0.f, 0.f};
    _Float16* Pme = &Pw[w][0];

    for (int kt = 0; kt < Sc; kt += 64) {
        // ---- S = Q @ K^T : B[n=key=l16][k=d=quad*8+j] from K[key][d]
        floatx4 sc4[4];
        #pragma unroll
        for (int nb = 0; nb < 4; ++nb) {
            const _Float16* kb = Kp + (size_t)(kt + nb * 16 + l16) * Dc + quad * 8;
            half8 b0 = *(const half8*)(kb);
            half8 b1 = *(const half8*)(kb + 32);
            floatx4 s = floatx4{0.f, 0.f, 0.f, 0.f};
            s = __builtin_amdgcn_mfma_f32_16x16x32_f16(aq0, b0, s, 0, 0, 0);
            s = __builtin_amdgcn_mfma_f32_16x16x32_f16(aq1, b1, s, 0, 0, 0);
            sc4[nb] = s;
        }
        #pragma unroll
        for (int nb = 0; nb < 4; ++nb) {
            const float ad = adder[kt + nb * 16 + l16];
            #pragma unroll
            for (int r = 0; r < 4; ++r) sc4[nb][r] += ad;
        }
        // ---- online softmax (C/D row = quad*4+r, col = l16)
        float mx[4];
        #pragma unroll
        for (int r = 0; r < 4; ++r)
            mx[r] = fmaxf(fmaxf(sc4[0][r], sc4[1][r]), fmaxf(sc4[2][r], sc4[3][r]));
        #pragma unroll
        for (int off = 1; off < 16; off <<= 1)
            #pragma unroll
            for (int r = 0; r < 4; ++r)
                mx[r] = fmaxf(mx[r], __shfl_xor(mx[r], off, 64));

        float alpha[4], rs[4];
        #pragma unroll
        for (int r = 0; r < 4; ++r) {
            const float mn = fmaxf(mrun[r], mx[r]);
            alpha[r] = __expf(mrun[r] - mn);
            mrun[r] = mn;
            float s = 0.f;
            #pragma unroll
            for (int nb = 0; nb < 4; ++nb) {
                const float p = __expf(sc4[nb][r] - mn);
                sc4[nb][r] = p;
                s += p;
            }
            rs[r] = s;
        }
        #pragma unroll
        for (int off = 1; off < 16; off <<= 1)
            #pragma unroll
            for (int r = 0; r < 4; ++r) rs[r] += __shfl_xor(rs[r], off, 64);
        #pragma unroll
        for (int r = 0; r < 4; ++r) lrun[r] = lrun[r] * alpha[r] + rs[r];
        #pragma unroll
        for (int nb = 0; nb < 4; ++nb)
            #pragma unroll
            for (int r = 0; r < 4; ++r) o[nb][r] *= alpha[r];

        // ---- P: C-layout -> LDS -> A-layout, barriered on both sides
        __syncthreads();
        #pragma unroll
        for (int nb = 0; nb < 4; ++nb)
            #pragma unroll
            for (int r = 0; r < 4; ++r)
                Pme[(quad * 4 + r) * 72 + nb * 16 + l16] = (_Float16)sc4[nb][r];
        __syncthreads();
        const half8 ap0 = *(const half8*)(Pme + l16 * 72 + quad * 8);
        const half8 ap1 = *(const half8*)(Pme + l16 * 72 + 32 + quad * 8);

        // ---- O += P @ V : B[n=d=l16][k=key=quad*8+j] from V^T[d][s]
        #pragma unroll
        for (int nb = 0; nb < 4; ++nb) {
            const _Float16* vb = Vp + (size_t)(nb * 16 + l16) * Sc + kt + quad * 8;
            half8 b0 = *(const half8*)(vb);
            half8 b1 = *(const half8*)(vb + 32);
            o[nb] = __builtin_amdgcn_mfma_f32_16x16x32_f16(ap0, b0, o[nb], 0, 0, 0);
            o[nb] = __builtin_amdgcn_mfma_f32_16x16x32_f16(ap1, b1, o[nb], 0, 0, 0);
        }
    }

    // ---- epilogue: out[b, s, h*64 + d]
    float* op = out + (size_t)bI * Sc * HIDc + h * Dc;
    #pragma unroll
    for (int r = 0; r < 4; ++r) {
        const float inv = 1.0f / lrun[r];
        const int q = qrow + quad * 4 + r;
        #pragma unroll
        for (int nb = 0; nb < 4; ++nb)
            op[(size_t)q * HIDc + nb * 16 + l16] = o[nb][r] * inv;
    }
}

// ---------------------------------------------------------------------------
extern "C" void kernel_launch(void* const* d_in, const int* in_sizes, int n_in,
                              void* d_out, int out_size, void* d_ws, size_t ws_size,
                              hipStream_t stream) {
    const float* x    = (const float*)d_in[0];
    const int*   mask = (const int*)  d_in[1];
    const float* Wq   = (const float*)d_in[2];
    const float* bq   = (const float*)d_in[3];
    const float* Wk   = (const float*)d_in[4];
    const float* bk   = (const float*)d_in[5];
    const float* Wv   = (const float*)d_in[6];
    const float* bv   = (const float*)d_in[7];
    float* out = (float*)d_out;

    // workspace (f16): qw 8MB | kw 8MB | vt 8MB = 24MB
    char* ws = (char*)d_ws;
    _Float16* qw = (_Float16*)(ws);
    _Float16* kw = (_Float16*)(ws + (size_t)8  * 1024 * 1024);
    _Float16* vt = (_Float16*)(ws + (size_t)16 * 1024 * 1024);

    qkv_proj_kernel<<<dim3(HIDc / 64, (Bc * Sc) / 64, 3), 256, 0, stream>>>(
        x, Wq, bq, Wk, bk, Wv, bv, qw, kw, vt);
    attn_kernel<<<dim3(Sc / 64, Bc * Hc), 256, 0, stream>>>(qw, kw, vt, mask, out);
}

// Round 5
// 436.589 us; speedup vs baseline: 2.3069x; 1.6533x over previous
//
#include <hip/hip_runtime.h>
#include <cstddef>

constexpr int Bc = 2, Sc = 2048, Hc = 16, Dc = 64, HIDc = 1024;
#define NEG_INF -10000.0f

typedef _Float16 half8  __attribute__((ext_vector_type(8)));  // MFMA A/B frag (4 VGPRs)
typedef float   floatx4 __attribute__((ext_vector_type(4)));  // MFMA C/D frag

// ---------------------------------------------------------------------------
// cvt_x: x fp32 [4096][1024] -> f16 same layout. 8 elements/thread.
// ---------------------------------------------------------------------------
__global__ __launch_bounds__(256) void cvt_x_kernel(const float* __restrict__ x,
                                                    _Float16* __restrict__ xh) {
    int i = (blockIdx.x * 256 + threadIdx.x) * 8;
    float4 a = *(const float4*)(x + i);
    float4 b = *(const float4*)(x + i + 4);
    half8 h;
    h[0] = (_Float16)a.x; h[1] = (_Float16)a.y; h[2] = (_Float16)a.z; h[3] = (_Float16)a.w;
    h[4] = (_Float16)b.x; h[5] = (_Float16)b.y; h[6] = (_Float16)b.z; h[7] = (_Float16)b.w;
    *(half8*)(xh + i) = h;
}

// ---------------------------------------------------------------------------
// cvt_w: W fp32 [k][n] -> Wt f16 [n][k] (transposed), per z in {q,k,v}.
// ---------------------------------------------------------------------------
__global__ __launch_bounds__(256) void cvt_w_kernel(const float* __restrict__ Wq,
                                                    const float* __restrict__ Wk,
                                                    const float* __restrict__ Wv,
                                                    _Float16* __restrict__ Wt) {
    const float* W = (blockIdx.z == 0) ? Wq : (blockIdx.z == 1) ? Wk : Wv;
    _Float16* out = Wt + (size_t)blockIdx.z * HIDc * HIDc;
    __shared__ _Float16 T[64][65];
    const int t = threadIdx.x;
    const int kb = blockIdx.x * 64, nb = blockIdx.y * 64;
    const int r = t >> 2, c4 = (t & 3) * 16;
    #pragma unroll
    for (int i = 0; i < 16; i += 4) {
        float4 a = *(const float4*)(W + (size_t)(kb + r) * HIDc + nb + c4 + i);
        T[c4 + i + 0][r] = (_Float16)a.x;
        T[c4 + i + 1][r] = (_Float16)a.y;
        T[c4 + i + 2][r] = (_Float16)a.z;
        T[c4 + i + 3][r] = (_Float16)a.w;
    }
    __syncthreads();
    const int n = t >> 2, k4 = (t & 3) * 16;
    half8 o0, o1;
    #pragma unroll
    for (int j = 0; j < 8; ++j) { o0[j] = T[n][k4 + j]; o1[j] = T[n][k4 + 8 + j]; }
    *(half8*)(out + (size_t)(nb + n) * HIDc + kb + k4)     = o0;
    *(half8*)(out + (size_t)(nb + n) * HIDc + kb + k4 + 8) = o1;
}

// ---------------------------------------------------------------------------
// proj: C = x @ W + bias via f16 MFMA. A = xh [m][k], B = Wt [n][k].
// 128x128 tile, BK=32, 4 waves x (64x64). STAGING FIX vs R3: a row of the
// tile is 32 f16 = 64 B; each thread (2 threads/row) stages its 16-element
// half-row with TWO uint4 loads (R3 loaded one -> half of LDS was garbage).
// z=0: Q/8 -> [b,h,s,d]; z=1: K -> [b,h,s,d]; z=2: V^T -> [b,h,d,s].
// ---------------------------------------------------------------------------
#define PSTR 40  // LDS row stride in f16 (80 B: 16B-aligned, 2-way-max banks)
__global__ __launch_bounds__(256) void proj_kernel(
    const _Float16* __restrict__ xh, const _Float16* __restrict__ Wt,
    const float* __restrict__ bq, const float* __restrict__ bk, const float* __restrict__ bv,
    _Float16* __restrict__ qw, _Float16* __restrict__ kw, _Float16* __restrict__ vt)
{
    const int z = blockIdx.z;
    const _Float16* Wz = Wt + (size_t)z * HIDc * HIDc;
    const float* bias = (z == 0) ? bq : (z == 1) ? bk : bv;

    __shared__ _Float16 As[128 * PSTR];
    __shared__ _Float16 Bs[128 * PSTR];

    const int t = threadIdx.x;
    const int lane = t & 63, w = t >> 6;
    const int quad = lane >> 4, l16 = lane & 15;
    const int m0 = blockIdx.y * 128, n0 = blockIdx.x * 128;
    const int wm = (w >> 1) * 64, wn = (w & 1) * 64;
    const int sr = t >> 1, sh = (t & 1) * 16;   // row, 16-f16 half-row offset

    floatx4 acc[4][4];
    #pragma unroll
    for (int mb = 0; mb < 4; ++mb)
        #pragma unroll
        for (int nb = 0; nb < 4; ++nb) acc[mb][nb] = floatx4{0.f, 0.f, 0.f, 0.f};

    for (int k0 = 0; k0 < HIDc; k0 += 32) {
        const _Float16* ap = xh + (size_t)(m0 + sr) * HIDc + k0 + sh;
        const _Float16* bp = Wz + (size_t)(n0 + sr) * HIDc + k0 + sh;
        uint4 a0 = *(const uint4*)(ap);
        uint4 a1 = *(const uint4*)(ap + 8);
        uint4 b0 = *(const uint4*)(bp);
        uint4 b1 = *(const uint4*)(bp + 8);
        __syncthreads();
        *(uint4*)(As + sr * PSTR + sh)     = a0;
        *(uint4*)(As + sr * PSTR + sh + 8) = a1;
        *(uint4*)(Bs + sr * PSTR + sh)     = b0;
        *(uint4*)(Bs + sr * PSTR + sh + 8) = b1;
        __syncthreads();

        half8 af[4], bf[4];
        #pragma unroll
        for (int mb = 0; mb < 4; ++mb)
            af[mb] = *(const half8*)(As + (wm + mb * 16 + l16) * PSTR + quad * 8);
        #pragma unroll
        for (int nb = 0; nb < 4; ++nb)
            bf[nb] = *(const half8*)(Bs + (wn + nb * 16 + l16) * PSTR + quad * 8);
        #pragma unroll
        for (int mb = 0; mb < 4; ++mb)
            #pragma unroll
            for (int nb = 0; nb < 4; ++nb)
                acc[mb][nb] = __builtin_amdgcn_mfma_f32_16x16x32_f16(
                    af[mb], bf[nb], acc[mb][nb], 0, 0, 0);
    }

    // epilogue: C/D mapping col=lane&15, row=quad*4+reg (m89/m91-verified)
    #pragma unroll
    for (int nb = 0; nb < 4; ++nb) {
        const int N = n0 + wn + nb * 16 + l16;
        const float bi = bias[N];
        const int h = N >> 6, d = N & 63;
        #pragma unroll
        for (int mb = 0; mb < 4; ++mb) {
            #pragma unroll
            for (int r = 0; r < 4; ++r) {
                const int M = m0 + wm + mb * 16 + quad * 4 + r;
                const int bI = M >> 11, s = M & (Sc - 1);
                const float v = acc[mb][nb][r] + bi;
                if (z == 0)
                    qw[(((size_t)(bI * Hc + h)) * Sc + s) * Dc + d] = (_Float16)(v * 0.125f);
                else if (z == 1)
                    kw[(((size_t)(bI * Hc + h)) * Sc + s) * Dc + d] = (_Float16)v;
                else
                    vt[(((size_t)(bI * Hc + h)) * Dc + d) * Sc + s] = (_Float16)v;
            }
        }
    }
}

// ---------------------------------------------------------------------------
// attn: flash attention, f16 MFMA — byte-identical to the R4 passing version.
// ---------------------------------------------------------------------------
__global__ __launch_bounds__(256) void attn_kernel(
    const _Float16* __restrict__ qw, const _Float16* __restrict__ kw,
    const _Float16* __restrict__ vt, const int* __restrict__ mask,
    float* __restrict__ out)
{
    __shared__ float adder[Sc];              // 8 KB additive mask
    __shared__ _Float16 Pw[4][16 * 72];      // 9 KB, per-wave P strips

    const int t = threadIdx.x;
    const int lane = t & 63, w = t >> 6;
    const int quad = lane >> 4, l16 = lane & 15;
    const int qt = blockIdx.x, bh = blockIdx.y;
    const int bI = bh >> 4, h = bh & 15;

    const _Float16* Qp = qw + (size_t)bh * Sc * Dc;
    const _Float16* Kp = kw + (size_t)bh * Sc * Dc;
    const _Float16* Vp = vt + (size_t)bh * Dc * Sc;

    {   // mask -> additive adder in LDS
        const int4* mp = (const int4*)(mask + bI * Sc);
        #pragma unroll
        for (int i = 0; i < 2; ++i) {
            int4 m4 = mp[t * 2 + i];
            int base = (t * 2 + i) * 4;
            adder[base + 0] = (1.0f - (float)m4.x) * NEG_INF;
            adder[base + 1] = (1.0f - (float)m4.y) * NEG_INF;
            adder[base + 2] = (1.0f - (float)m4.z) * NEG_INF;
            adder[base + 3] = (1.0f - (float)m4.w) * NEG_INF;
        }
    }
    __syncthreads();

    const int qrow = qt * 64 + w * 16;
    const half8 aq0 = *(const half8*)(Qp + (size_t)(qrow + l16) * Dc + quad * 8);
    const half8 aq1 = *(const half8*)(Qp + (size_t)(qrow + l16) * Dc + 32 + quad * 8);

    floatx4 o[4];
    #pragma unroll
    for (int nb = 0; nb < 4; ++nb) o[nb] = floatx4{0.f, 0.f, 0.f, 0.f};
    float mrun[4] = {-1e30f, -1e30f, -1e30f, -1e30f};
    float lrun[4] = {0.f, 0.f, 0.f, 0.f};
    _Float16* Pme = &Pw[w][0];

    for (int kt = 0; kt < Sc; kt += 64) {
        // ---- S = Q @ K^T : B[n=key=l16][k=d=quad*8+j] from K[key][d]
        floatx4 sc4[4];
        #pragma unroll
        for (int nb = 0; nb < 4; ++nb) {
            const _Float16* kb = Kp + (size_t)(kt + nb * 16 + l16) * Dc + quad * 8;
            half8 b0 = *(const half8*)(kb);
            half8 b1 = *(const half8*)(kb + 32);
            floatx4 s = floatx4{0.f, 0.f, 0.f, 0.f};
            s = __builtin_amdgcn_mfma_f32_16x16x32_f16(aq0, b0, s, 0, 0, 0);
            s = __builtin_amdgcn_mfma_f32_16x16x32_f16(aq1, b1, s, 0, 0, 0);
            sc4[nb] = s;
        }
        #pragma unroll
        for (int nb = 0; nb < 4; ++nb) {
            const float ad = adder[kt + nb * 16 + l16];
            #pragma unroll
            for (int r = 0; r < 4; ++r) sc4[nb][r] += ad;
        }
        // ---- online softmax (C/D row = quad*4+r, col = l16)
        float mx[4];
        #pragma unroll
        for (int r = 0; r < 4; ++r)
            mx[r] = fmaxf(fmaxf(sc4[0][r], sc4[1][r]), fmaxf(sc4[2][r], sc4[3][r]));
        #pragma unroll
        for (int off = 1; off < 16; off <<= 1)
            #pragma unroll
            for (int r = 0; r < 4; ++r)
                mx[r] = fmaxf(mx[r], __shfl_xor(mx[r], off, 64));

        float alpha[4], rs[4];
        #pragma unroll
        for (int r = 0; r < 4; ++r) {
            const float mn = fmaxf(mrun[r], mx[r]);
            alpha[r] = __expf(mrun[r] - mn);
            mrun[r] = mn;
            float s = 0.f;
            #pragma unroll
            for (int nb = 0; nb < 4; ++nb) {
                const float p = __expf(sc4[nb][r] - mn);
                sc4[nb][r] = p;
                s += p;
            }
            rs[r] = s;
        }
        #pragma unroll
        for (int off = 1; off < 16; off <<= 1)
            #pragma unroll
            for (int r = 0; r < 4; ++r) rs[r] += __shfl_xor(rs[r], off, 64);
        #pragma unroll
        for (int r = 0; r < 4; ++r) lrun[r] = lrun[r] * alpha[r] + rs[r];
        #pragma unroll
        for (int nb = 0; nb < 4; ++nb)
            #pragma unroll
            for (int r = 0; r < 4; ++r) o[nb][r] *= alpha[r];

        // ---- P: C-layout -> LDS -> A-layout, barriered on both sides
        __syncthreads();
        #pragma unroll
        for (int nb = 0; nb < 4; ++nb)
            #pragma unroll
            for (int r = 0; r < 4; ++r)
                Pme[(quad * 4 + r) * 72 + nb * 16 + l16] = (_Float16)sc4[nb][r];
        __syncthreads();
        const half8 ap0 = *(const half8*)(Pme + l16 * 72 + quad * 8);
        const half8 ap1 = *(const half8*)(Pme + l16 * 72 + 32 + quad * 8);

        // ---- O += P @ V : B[n=d=l16][k=key=quad*8+j] from V^T[d][s]
        #pragma unroll
        for (int nb = 0; nb < 4; ++nb) {
            const _Float16* vb = Vp + (size_t)(nb * 16 + l16) * Sc + kt + quad * 8;
            half8 b0 = *(const half8*)(vb);
            half8 b1 = *(const half8*)(vb + 32);
            o[nb] = __builtin_amdgcn_mfma_f32_16x16x32_f16(ap0, b0, o[nb], 0, 0, 0);
            o[nb] = __builtin_amdgcn_mfma_f32_16x16x32_f16(ap1, b1, o[nb], 0, 0, 0);
        }
    }

    // ---- epilogue: out[b, s, h*64 + d]
    float* op = out + (size_t)bI * Sc * HIDc + h * Dc;
    #pragma unroll
    for (int r = 0; r < 4; ++r) {
        const float inv = 1.0f / lrun[r];
        const int q = qrow + quad * 4 + r;
        #pragma unroll
        for (int nb = 0; nb < 4; ++nb)
            op[(size_t)q * HIDc + nb * 16 + l16] = o[nb][r] * inv;
    }
}

// ---------------------------------------------------------------------------
extern "C" void kernel_launch(void* const* d_in, const int* in_sizes, int n_in,
                              void* d_out, int out_size, void* d_ws, size_t ws_size,
                              hipStream_t stream) {
    const float* x    = (const float*)d_in[0];
    const int*   mask = (const int*)  d_in[1];
    const float* Wq   = (const float*)d_in[2];
    const float* bq   = (const float*)d_in[3];
    const float* Wk   = (const float*)d_in[4];
    const float* bk   = (const float*)d_in[5];
    const float* Wv   = (const float*)d_in[6];
    const float* bv   = (const float*)d_in[7];
    float* out = (float*)d_out;

    // workspace (f16): xh 8MB | Wt 6MB | qw 8MB | kw 8MB | vt 8MB = 38MB
    char* ws = (char*)d_ws;
    _Float16* xh = (_Float16*)(ws);
    _Float16* Wt = (_Float16*)(ws + (size_t)8  * 1024 * 1024);
    _Float16* qw = (_Float16*)(ws + (size_t)14 * 1024 * 1024);
    _Float16* kw = (_Float16*)(ws + (size_t)22 * 1024 * 1024);
    _Float16* vt = (_Float16*)(ws + (size_t)30 * 1024 * 1024);

    cvt_x_kernel<<<(Bc * Sc * HIDc) / (256 * 8), 256, 0, stream>>>(x, xh);
    cvt_w_kernel<<<dim3(HIDc / 64, HIDc / 64, 3), 256, 0, stream>>>(Wq, Wk, Wv, Wt);
    proj_kernel<<<dim3(HIDc / 128, (Bc * Sc) / 128, 3), 256, 0, stream>>>(
        xh, Wt, bq, bk, bv, qw, kw, vt);
    attn_kernel<<<dim3(Sc / 64, Bc * Hc), 256, 0, stream>>>(qw, kw, vt, mask, out);
}

// Round 6
// 267.214 us; speedup vs baseline: 3.7691x; 1.6339x over previous
//
#include <hip/hip_runtime.h>
#include <cstddef>

constexpr int Bc = 2, Sc = 2048, Hc = 16, Dc = 64, HIDc = 1024;
#define NEG_INF -10000.0f

typedef _Float16 half8  __attribute__((ext_vector_type(8)));  // MFMA A/B frag (4 VGPRs)
typedef float   floatx4 __attribute__((ext_vector_type(4)));  // MFMA C/D frag

// ---------------------------------------------------------------------------
// cvt_x: x fp32 [4096][1024] -> f16 same layout. 8 elements/thread.
// ---------------------------------------------------------------------------
__global__ __launch_bounds__(256) void cvt_x_kernel(const float* __restrict__ x,
                                                    _Float16* __restrict__ xh) {
    int i = (blockIdx.x * 256 + threadIdx.x) * 8;
    float4 a = *(const float4*)(x + i);
    float4 b = *(const float4*)(x + i + 4);
    half8 h;
    h[0] = (_Float16)a.x; h[1] = (_Float16)a.y; h[2] = (_Float16)a.z; h[3] = (_Float16)a.w;
    h[4] = (_Float16)b.x; h[5] = (_Float16)b.y; h[6] = (_Float16)b.z; h[7] = (_Float16)b.w;
    *(half8*)(xh + i) = h;
}

// ---------------------------------------------------------------------------
// cvt_w: W fp32 [k][n] -> Wt f16 [n][k] (transposed), per z in {q,k,v}.
// ---------------------------------------------------------------------------
__global__ __launch_bounds__(256) void cvt_w_kernel(const float* __restrict__ Wq,
                                                    const float* __restrict__ Wk,
                                                    const float* __restrict__ Wv,
                                                    _Float16* __restrict__ Wt) {
    const float* W = (blockIdx.z == 0) ? Wq : (blockIdx.z == 1) ? Wk : Wv;
    _Float16* out = Wt + (size_t)blockIdx.z * HIDc * HIDc;
    __shared__ _Float16 T[64][65];
    const int t = threadIdx.x;
    const int kb = blockIdx.x * 64, nb = blockIdx.y * 64;
    const int r = t >> 2, c4 = (t & 3) * 16;
    #pragma unroll
    for (int i = 0; i < 16; i += 4) {
        float4 a = *(const float4*)(W + (size_t)(kb + r) * HIDc + nb + c4 + i);
        T[c4 + i + 0][r] = (_Float16)a.x;
        T[c4 + i + 1][r] = (_Float16)a.y;
        T[c4 + i + 2][r] = (_Float16)a.z;
        T[c4 + i + 3][r] = (_Float16)a.w;
    }
    __syncthreads();
    const int n = t >> 2, k4 = (t & 3) * 16;
    half8 o0, o1;
    #pragma unroll
    for (int j = 0; j < 8; ++j) { o0[j] = T[n][k4 + j]; o1[j] = T[n][k4 + 8 + j]; }
    *(half8*)(out + (size_t)(nb + n) * HIDc + kb + k4)     = o0;
    *(half8*)(out + (size_t)(nb + n) * HIDc + kb + k4 + 8) = o1;
}

// ---------------------------------------------------------------------------
// proj: unchanged from R5 (passing). C = x@W + bias via f16 MFMA, 128x128
// tile, BK=32, 4 waves x (64x64), full half-row staging (2x uint4).
// ---------------------------------------------------------------------------
#define PSTR 40
__global__ __launch_bounds__(256) void proj_kernel(
    const _Float16* __restrict__ xh, const _Float16* __restrict__ Wt,
    const float* __restrict__ bq, const float* __restrict__ bk, const float* __restrict__ bv,
    _Float16* __restrict__ qw, _Float16* __restrict__ kw, _Float16* __restrict__ vt)
{
    const int z = blockIdx.z;
    const _Float16* Wz = Wt + (size_t)z * HIDc * HIDc;
    const float* bias = (z == 0) ? bq : (z == 1) ? bk : bv;

    __shared__ _Float16 As[128 * PSTR];
    __shared__ _Float16 Bs[128 * PSTR];

    const int t = threadIdx.x;
    const int lane = t & 63, w = t >> 6;
    const int quad = lane >> 4, l16 = lane & 15;
    const int m0 = blockIdx.y * 128, n0 = blockIdx.x * 128;
    const int wm = (w >> 1) * 64, wn = (w & 1) * 64;
    const int sr = t >> 1, sh = (t & 1) * 16;

    floatx4 acc[4][4];
    #pragma unroll
    for (int mb = 0; mb < 4; ++mb)
        #pragma unroll
        for (int nb = 0; nb < 4; ++nb) acc[mb][nb] = floatx4{0.f, 0.f, 0.f, 0.f};

    for (int k0 = 0; k0 < HIDc; k0 += 32) {
        const _Float16* ap = xh + (size_t)(m0 + sr) * HIDc + k0 + sh;
        const _Float16* bp = Wz + (size_t)(n0 + sr) * HIDc + k0 + sh;
        uint4 a0 = *(const uint4*)(ap);
        uint4 a1 = *(const uint4*)(ap + 8);
        uint4 b0 = *(const uint4*)(bp);
        uint4 b1 = *(const uint4*)(bp + 8);
        __syncthreads();
        *(uint4*)(As + sr * PSTR + sh)     = a0;
        *(uint4*)(As + sr * PSTR + sh + 8) = a1;
        *(uint4*)(Bs + sr * PSTR + sh)     = b0;
        *(uint4*)(Bs + sr * PSTR + sh + 8) = b1;
        __syncthreads();

        half8 af[4], bf[4];
        #pragma unroll
        for (int mb = 0; mb < 4; ++mb)
            af[mb] = *(const half8*)(As + (wm + mb * 16 + l16) * PSTR + quad * 8);
        #pragma unroll
        for (int nb = 0; nb < 4; ++nb)
            bf[nb] = *(const half8*)(Bs + (wn + nb * 16 + l16) * PSTR + quad * 8);
        #pragma unroll
        for (int mb = 0; mb < 4; ++mb)
            #pragma unroll
            for (int nb = 0; nb < 4; ++nb)
                acc[mb][nb] = __builtin_amdgcn_mfma_f32_16x16x32_f16(
                    af[mb], bf[nb], acc[mb][nb], 0, 0, 0);
    }

    #pragma unroll
    for (int nb = 0; nb < 4; ++nb) {
        const int N = n0 + wn + nb * 16 + l16;
        const float bi = bias[N];
        const int h = N >> 6, d = N & 63;
        #pragma unroll
        for (int mb = 0; mb < 4; ++mb) {
            #pragma unroll
            for (int r = 0; r < 4; ++r) {
                const int M = m0 + wm + mb * 16 + quad * 4 + r;
                const int bI = M >> 11, s = M & (Sc - 1);
                const float v = acc[mb][nb][r] + bi;
                if (z == 0)
                    qw[(((size_t)(bI * Hc + h)) * Sc + s) * Dc + d] = (_Float16)(v * 0.125f);
                else if (z == 1)
                    kw[(((size_t)(bI * Hc + h)) * Sc + s) * Dc + d] = (_Float16)v;
                else
                    vt[(((size_t)(bI * Hc + h)) * Dc + d) * Sc + s] = (_Float16)v;
            }
        }
    }
}

// ---------------------------------------------------------------------------
// attn R6: 32 q-rows/wave (2 frag-sets), register K-prefetch, NO barriers in
// the key loop. P strips are per-wave (Pw[w]); within a wave DS ops complete
// in order and the compiler sees the aliasing -> barrier-free is safe, and
// necessary: any s_barrier would drain vmcnt(0) and kill the K-prefetch.
// Block = 4 waves = 128 q-rows; grid (16, 32).
// ---------------------------------------------------------------------------
__global__ __launch_bounds__(256, 2) void attn_kernel(
    const _Float16* __restrict__ qw, const _Float16* __restrict__ kw,
    const _Float16* __restrict__ vt, const int* __restrict__ mask,
    float* __restrict__ out)
{
    __shared__ float adder[Sc];               // 8 KB additive mask
    __shared__ _Float16 Pw[4][32 * 72];       // 18 KB, per-wave P strips

    const int t = threadIdx.x;
    const int lane = t & 63, w = t >> 6;
    const int quad = lane >> 4, l16 = lane & 15;
    const int bh = blockIdx.y;
    const int bI = bh >> 4, h = bh & 15;

    const _Float16* Qp = qw + (size_t)bh * Sc * Dc;
    const _Float16* Kp = kw + (size_t)bh * Sc * Dc;
    const _Float16* Vp = vt + (size_t)bh * Dc * Sc;

    {   // mask -> additive adder in LDS (once per block)
        const int4* mp = (const int4*)(mask + bI * Sc);
        #pragma unroll
        for (int i = 0; i < 2; ++i) {
            int4 m4 = mp[t * 2 + i];
            int base = (t * 2 + i) * 4;
            adder[base + 0] = (1.0f - (float)m4.x) * NEG_INF;
            adder[base + 1] = (1.0f - (float)m4.y) * NEG_INF;
            adder[base + 2] = (1.0f - (float)m4.z) * NEG_INF;
            adder[base + 3] = (1.0f - (float)m4.w) * NEG_INF;
        }
    }
    __syncthreads();   // adder ready (only block-wide barrier in the kernel)

    const int qrow = blockIdx.x * 128 + w * 32;
    // Q A-frags for both 16-row sets: A[m=l16][k=quad*8+j]
    half8 aq[2][2];
    #pragma unroll
    for (int s = 0; s < 2; ++s)
        #pragma unroll
        for (int hh = 0; hh < 2; ++hh)
            aq[s][hh] = *(const half8*)(Qp + (size_t)(qrow + 16 * s + l16) * Dc
                                        + hh * 32 + quad * 8);

    floatx4 o[2][4];
    float mrun[2][4], lrun[2][4];
    #pragma unroll
    for (int s = 0; s < 2; ++s)
        #pragma unroll
        for (int nb = 0; nb < 4; ++nb) {
            o[s][nb] = floatx4{0.f, 0.f, 0.f, 0.f};
            mrun[s][nb] = -1e30f;   // indexed [s][r] below; init all
            lrun[s][nb] = 0.f;
        }
    _Float16* Pme = &Pw[w][0];

    // preload K-tile 0: B[n=key=l16][k=d=quad*8+j] from K[key][d]
    half8 kb[4][2];
    #pragma unroll
    for (int nb = 0; nb < 4; ++nb)
        #pragma unroll
        for (int hh = 0; hh < 2; ++hh)
            kb[nb][hh] = *(const half8*)(Kp + (size_t)(nb * 16 + l16) * Dc
                                         + hh * 32 + quad * 8);

    for (int kt = 0; kt < Sc; kt += 64) {
        // ---- S = Q @ K^T (both sets share kb)
        floatx4 sc[2][4];
        #pragma unroll
        for (int s = 0; s < 2; ++s)
            #pragma unroll
            for (int nb = 0; nb < 4; ++nb) {
                floatx4 acc = floatx4{0.f, 0.f, 0.f, 0.f};
                acc = __builtin_amdgcn_mfma_f32_16x16x32_f16(aq[s][0], kb[nb][0], acc, 0, 0, 0);
                acc = __builtin_amdgcn_mfma_f32_16x16x32_f16(aq[s][1], kb[nb][1], acc, 0, 0, 0);
                sc[s][nb] = acc;
            }

        // ---- issue V loads (used after softmax) and K prefetch (next tile)
        half8 vb[4][2], kbn[4][2];
        #pragma unroll
        for (int nb = 0; nb < 4; ++nb)
            #pragma unroll
            for (int hh = 0; hh < 2; ++hh)
                vb[nb][hh] = *(const half8*)(Vp + (size_t)(nb * 16 + l16) * Sc
                                             + kt + hh * 32 + quad * 8);
        const int ktn = (kt + 64 < Sc) ? kt + 64 : 0;
        #pragma unroll
        for (int nb = 0; nb < 4; ++nb)
            #pragma unroll
            for (int hh = 0; hh < 2; ++hh)
                kbn[nb][hh] = *(const half8*)(Kp + (size_t)(ktn + nb * 16 + l16) * Dc
                                              + hh * 32 + quad * 8);

        // ---- mask add (column = kt + nb*16 + l16, same for both sets)
        float ad[4];
        #pragma unroll
        for (int nb = 0; nb < 4; ++nb) ad[nb] = adder[kt + nb * 16 + l16];
        #pragma unroll
        for (int s = 0; s < 2; ++s)
            #pragma unroll
            for (int nb = 0; nb < 4; ++nb)
                #pragma unroll
                for (int r = 0; r < 4; ++r) sc[s][nb][r] += ad[nb];

        // ---- online softmax, two independent sets (ILP)
        #pragma unroll
        for (int s = 0; s < 2; ++s) {
            float mx[4];
            #pragma unroll
            for (int r = 0; r < 4; ++r)
                mx[r] = fmaxf(fmaxf(sc[s][0][r], sc[s][1][r]),
                              fmaxf(sc[s][2][r], sc[s][3][r]));
            #pragma unroll
            for (int off = 1; off < 16; off <<= 1)
                #pragma unroll
                for (int r = 0; r < 4; ++r)
                    mx[r] = fmaxf(mx[r], __shfl_xor(mx[r], off, 64));

            float rs[4];
            #pragma unroll
            for (int r = 0; r < 4; ++r) {
                const float mn = fmaxf(mrun[s][r], mx[r]);
                const float al = __expf(mrun[s][r] - mn);
                mrun[s][r] = mn;
                float sum = 0.f;
                #pragma unroll
                for (int nb = 0; nb < 4; ++nb) {
                    const float p = __expf(sc[s][nb][r] - mn);
                    sc[s][nb][r] = p;
                    sum += p;
                }
                rs[r] = sum;
                lrun[s][r] *= al;
                #pragma unroll
                for (int nb = 0; nb < 4; ++nb) o[s][nb][r] *= al;
            }
            #pragma unroll
            for (int off = 1; off < 16; off <<= 1)
                #pragma unroll
                for (int r = 0; r < 4; ++r) rs[r] += __shfl_xor(rs[r], off, 64);
            #pragma unroll
            for (int r = 0; r < 4; ++r) lrun[s][r] += rs[r];
        }

        // ---- P: C-layout -> per-wave LDS strip -> A-layout (no barriers;
        //      wave-internal, DS in-order, compiler-visible aliasing)
        #pragma unroll
        for (int s = 0; s < 2; ++s)
            #pragma unroll
            for (int nb = 0; nb < 4; ++nb)
                #pragma unroll
                for (int r = 0; r < 4; ++r)
                    Pme[(16 * s + quad * 4 + r) * 72 + nb * 16 + l16] =
                        (_Float16)sc[s][nb][r];
        half8 ap[2][2];
        #pragma unroll
        for (int s = 0; s < 2; ++s)
            #pragma unroll
            for (int hh = 0; hh < 2; ++hh)
                ap[s][hh] = *(const half8*)(Pme + (16 * s + l16) * 72 + hh * 32 + quad * 8);

        // ---- O += P @ V : B[n=d=l16][k=key] from V^T[d][s]
        #pragma unroll
        for (int s = 0; s < 2; ++s)
            #pragma unroll
            for (int nb = 0; nb < 4; ++nb) {
                o[s][nb] = __builtin_amdgcn_mfma_f32_16x16x32_f16(ap[s][0], vb[nb][0], o[s][nb], 0, 0, 0);
                o[s][nb] = __builtin_amdgcn_mfma_f32_16x16x32_f16(ap[s][1], vb[nb][1], o[s][nb], 0, 0, 0);
            }

        // ---- rotate prefetched K
        #pragma unroll
        for (int nb = 0; nb < 4; ++nb)
            #pragma unroll
            for (int hh = 0; hh < 2; ++hh) kb[nb][hh] = kbn[nb][hh];
    }

    // ---- epilogue: out[b, q, h*64 + d]
    float* op = out + (size_t)bI * Sc * HIDc + h * Dc;
    #pragma unroll
    for (int s = 0; s < 2; ++s)
        #pragma unroll
        for (int r = 0; r < 4; ++r) {
            const float inv = 1.0f / lrun[s][r];
            const int q = qrow + 16 * s + quad * 4 + r;
            #pragma unroll
            for (int nb = 0; nb < 4; ++nb)
                op[(size_t)q * HIDc + nb * 16 + l16] = o[s][nb][r] * inv;
        }
}

// ---------------------------------------------------------------------------
extern "C" void kernel_launch(void* const* d_in, const int* in_sizes, int n_in,
                              void* d_out, int out_size, void* d_ws, size_t ws_size,
                              hipStream_t stream) {
    const float* x    = (const float*)d_in[0];
    const int*   mask = (const int*)  d_in[1];
    const float* Wq   = (const float*)d_in[2];
    const float* bq   = (const float*)d_in[3];
    const float* Wk   = (const float*)d_in[4];
    const float* bk   = (const float*)d_in[5];
    const float* Wv   = (const float*)d_in[6];
    const float* bv   = (const float*)d_in[7];
    float* out = (float*)d_out;

    // workspace (f16): xh 8MB | Wt 6MB | qw 8MB | kw 8MB | vt 8MB = 38MB
    char* ws = (char*)d_ws;
    _Float16* xh = (_Float16*)(ws);
    _Float16* Wt = (_Float16*)(ws + (size_t)8  * 1024 * 1024);
    _Float16* qw = (_Float16*)(ws + (size_t)14 * 1024 * 1024);
    _Float16* kw = (_Float16*)(ws + (size_t)22 * 1024 * 1024);
    _Float16* vt = (_Float16*)(ws + (size_t)30 * 1024 * 1024);

    cvt_x_kernel<<<(Bc * Sc * HIDc) / (256 * 8), 256, 0, stream>>>(x, xh);
    cvt_w_kernel<<<dim3(HIDc / 64, HIDc / 64, 3), 256, 0, stream>>>(Wq, Wk, Wv, Wt);
    proj_kernel<<<dim3(HIDc / 128, (Bc * Sc) / 128, 3), 256, 0, stream>>>(
        xh, Wt, bq, bk, bv, qw, kw, vt);
    attn_kernel<<<dim3(Sc / 128, Bc * Hc), 256, 0, stream>>>(qw, kw, vt, mask, out);
}